// Round 1
// baseline (954.129 us; speedup 1.0000x reference)
//
#include <hip/hip_runtime.h>
#include <math.h>

namespace {
constexpr int NIMG = 16;
constexpr int ICH  = 3;
constexpr int OCH  = 64;
constexpr int KS   = 7;
constexpr int H    = 512;
constexpr int W    = 512;
constexpr int TH   = 32;   // output tile height per block
constexpr int TW   = 64;   // output tile width per block
constexpr int XH   = TH + 6;
constexpr int XW   = TW + 6;
constexpr int XWP  = 76;   // LDS pitch (floats): mult of 4 (16B align), 4*76%32=16 spreads pi groups
}

__global__ __launch_bounds__(256)
void ridgelet_conv(const float* __restrict__ x,
                   const float* __restrict__ scales,
                   const float* __restrict__ dirs,
                   const float* __restrict__ poss,
                   float* __restrict__ out)
{
    __shared__ float xs[XH][XWP];          // channel-summed input tile (padded)
    __shared__ float wl[KS * KS][OCH];     // ridgelet filter bank, [k][oc]

    const int tid = threadIdx.x;
    const int tw0 = blockIdx.x * TW;
    const int th0 = blockIdx.y * TH;
    const int n   = blockIdx.z;

    // ---- generate filter bank into LDS (cheap: ~12 exp-pairs/thread) ----
    for (int idx = tid; idx < KS * KS * OCH; idx += 256) {
        const int k  = idx >> 6;      // 0..48
        const int oc = idx & 63;
        const int kh = k / 7;
        const int kw = k - kh * 7;
        const float c1 = (float)(kh - 3);
        const float c2 = (float)(kw - 3);
        const float d  = dirs[oc];
        const float tc = (c1 * cosf(d) + c2 * sinf(d) - poss[oc]) / scales[oc];
        const float t2 = tc * tc;
        wl[k][oc] = expf(-0.5f * t2) - 0.5f * expf(-0.125f * t2);
    }

    // ---- stage channel-summed, zero-padded input tile ----
    const float* xb = x + (size_t)n * ICH * H * W;
    for (int idx = tid; idx < XH * XW; idx += 256) {
        const int r  = idx / XW;
        const int c  = idx - r * XW;
        const int gh = th0 + r - 3;
        const int gw = tw0 + c - 3;
        float s = 0.0f;
        if ((unsigned)gh < (unsigned)H && (unsigned)gw < (unsigned)W) {
            const size_t o = (size_t)gh * W + gw;
            s = xb[o] + xb[o + (size_t)H * W] + xb[o + 2 * (size_t)H * W];
        }
        xs[r][c] = s;
    }
    __syncthreads();

    // ---- compute: 256 threads = 128 pixel-threads x 2 channel-groups ----
    // pixel-thread tile: 4 rows x 4 cols; channel group: 4 consecutive oc
    const int g  = tid >> 7;          // 0..1
    const int px = tid & 127;
    const int pj = px & 15;           // 16 col groups  -> c0 = 0..60
    const int pi = px >> 4;           // 8 row groups   -> r0 = 0..28
    const int r0 = pi * 4;
    const int c0 = pj * 4;

    float* ob = out + (size_t)n * OCH * H * W
                    + (size_t)(th0 + r0) * W + (tw0 + c0);

    #pragma unroll 1
    for (int it = 0; it < 8; ++it) {
        const int ocb = it * 8 + g * 4;   // this thread's 4 output channels

        float acc[4][4][4];               // [row i][col j][oc c]
        #pragma unroll
        for (int i = 0; i < 4; ++i)
            #pragma unroll
            for (int j = 0; j < 4; ++j)
                #pragma unroll
                for (int c = 0; c < 4; ++c)
                    acc[i][j][c] = 0.0f;

        #pragma unroll
        for (int kh = 0; kh < KS; ++kh) {
            // load the 4 input rows this kh needs: cols c0 .. c0+11 (12 floats)
            float rv[4][12];
            #pragma unroll
            for (int i = 0; i < 4; ++i) {
                const float* rp = &xs[r0 + kh + i][c0];
                const float4 a = *(const float4*)(rp);
                const float4 b = *(const float4*)(rp + 4);
                const float4 cc = *(const float4*)(rp + 8);
                rv[i][0] = a.x;  rv[i][1] = a.y;  rv[i][2]  = a.z;  rv[i][3]  = a.w;
                rv[i][4] = b.x;  rv[i][5] = b.y;  rv[i][6]  = b.z;  rv[i][7]  = b.w;
                rv[i][8] = cc.x; rv[i][9] = cc.y; rv[i][10] = cc.z; rv[i][11] = cc.w;
            }
            #pragma unroll
            for (int kw = 0; kw < KS; ++kw) {
                // 4 channels' weights: uniform address per wave -> LDS broadcast
                const float4 w4 = *(const float4*)&wl[kh * 7 + kw][ocb];
                const float wv[4] = {w4.x, w4.y, w4.z, w4.w};
                #pragma unroll
                for (int i = 0; i < 4; ++i) {
                    #pragma unroll
                    for (int j = 0; j < 4; ++j) {
                        const float v = rv[i][j + kw];
                        #pragma unroll
                        for (int c = 0; c < 4; ++c)
                            acc[i][j][c] = fmaf(v, wv[c], acc[i][j][c]);
                    }
                }
            }
        }

        // ---- store: register-transpose so float4 = 4 consecutive w ----
        #pragma unroll
        for (int i = 0; i < 4; ++i) {
            #pragma unroll
            for (int c = 0; c < 4; ++c) {
                const float4 st = make_float4(acc[i][0][c], acc[i][1][c],
                                              acc[i][2][c], acc[i][3][c]);
                *(float4*)(ob + (size_t)(ocb + c) * H * W + (size_t)i * W) = st;
            }
        }
    }
}

extern "C" void kernel_launch(void* const* d_in, const int* in_sizes, int n_in,
                              void* d_out, int out_size, void* d_ws, size_t ws_size,
                              hipStream_t stream)
{
    const float* x  = (const float*)d_in[0];
    const float* sc = (const float*)d_in[1];
    const float* di = (const float*)d_in[2];
    const float* po = (const float*)d_in[3];
    float* outp     = (float*)d_out;

    dim3 grid(W / TW, H / TH, NIMG);   // 8 x 16 x 16 = 2048 blocks
    ridgelet_conv<<<grid, dim3(256), 0, stream>>>(x, sc, di, po, outp);
}